// Round 1
// baseline (1739.171 us; speedup 1.0000x reference)
//
#include <hip/hip_runtime.h>

#define NPTS 65536
#define V 4096
#define C 32
#define HH 64
#define WW 64
#define NB 16

#define TS 16
#define TP 18   // tile + halo
#define CP 36   // padded channel stride (floats), 144B, keeps float4 aligned & ~2-way banks

// ---- 0.5*||e_v||^2 ----
__global__ void k_en(const float* __restrict__ emb, float* __restrict__ en) {
    int v = blockIdx.x * 256 + threadIdx.x;
    const float4* e4 = (const float4*)(emb + v * C);
    float s = 0.f;
#pragma unroll
    for (int j = 0; j < 8; ++j) {
        float4 q = e4[j];
        s += q.x*q.x + q.y*q.y + q.z*q.z + q.w*q.w;
    }
    en[v] = 0.5f * s;
}

// ---- transpose conv weights OIHW -> [i][ky][kx][o] so o-rows are contiguous ----
__global__ void k_wt(const float* __restrict__ cw, float* __restrict__ wt) {
    int t = blockIdx.x * 256 + threadIdx.x;
    if (t >= C * C * 9) return;
    int o = t & 31;
    int r = t >> 5;            // (i*3+ky)*3+kx
    int kx = r % 3;
    int ky = (r / 3) % 3;
    int i  = r / 9;
    wt[t] = cw[((o * C + i) * 3 + ky) * 3 + kx];
}

// ---- nearest-code argmin: key = 0.5||e||^2 - x.e ----
__global__ __launch_bounds__(256) void k_argmin(const float* __restrict__ f,
                                                const float* __restrict__ emb,
                                                const float* __restrict__ en,
                                                int* __restrict__ idx) {
    int n = blockIdx.x * 256 + threadIdx.x;
    int b = n >> 12, pix = n & 4095;
    float x[C];
#pragma unroll
    for (int c = 0; c < C; ++c) x[c] = f[(b * C + c) * 4096 + pix];

    float best = 3.4e38f;
    int bi = 0;
#pragma unroll 2
    for (int v = 0; v < V; ++v) {
        const float4* e4 = (const float4*)(emb + v * C);   // wave-uniform -> s_load
        float d = en[v];
#pragma unroll
        for (int j = 0; j < 8; ++j) {
            float4 q = e4[j];
            d = fmaf(q.x, -x[4*j+0], d);
            d = fmaf(q.y, -x[4*j+1], d);
            d = fmaf(q.z, -x[4*j+2], d);
            d = fmaf(q.w, -x[4*j+3], d);
        }
        if (d < best) { best = d; bi = v; }   // strict <: first-min wins (np.argmin)
    }
    idx[n] = bi;
}

// ---- fused gather + conv3x3 + Phi + output + loss partials ----
__global__ __launch_bounds__(256) void k_conv(const float* __restrict__ f,
                                              const float* __restrict__ emb,
                                              const int* __restrict__ idx,
                                              const float* __restrict__ wt,
                                              const float* __restrict__ cb,
                                              float* __restrict__ out,
                                              float* __restrict__ partial) {
    __shared__ float tile[TP * TP * CP];   // [y][x][c] padded, ~46.7KB
    __shared__ float red[256];

    int blk = blockIdx.x;
    int b = blk >> 4, t = blk & 15;
    int y0 = (t >> 2) * TS, x0 = (t & 3) * TS;
    int tid = threadIdx.x;

    // gather halo tile from codebook via idx
    for (int p = tid; p < TP * TP; p += 256) {
        int gy = y0 + (p / TP) - 1;
        int gx = x0 + (p % TP) - 1;
        float4 e[8];
        if (gy >= 0 && gy < HH && gx >= 0 && gx < WW) {
            int id = idx[b * 4096 + gy * WW + gx];
            const float4* e4 = (const float4*)(emb + id * C);
#pragma unroll
            for (int j = 0; j < 8; ++j) e[j] = e4[j];
        } else {
#pragma unroll
            for (int j = 0; j < 8; ++j) e[j] = make_float4(0.f, 0.f, 0.f, 0.f);
        }
        float4* dst = (float4*)(tile + p * CP);
#pragma unroll
        for (int j = 0; j < 8; ++j) dst[j] = e[j];
    }
    __syncthreads();

    int ly = tid >> 4, lx = tid & 15;
    float acc[C];
#pragma unroll
    for (int o = 0; o < C; ++o) acc[o] = cb[o];   // uniform s_load

#pragma unroll
    for (int ky = 0; ky < 3; ++ky)
#pragma unroll
    for (int kx = 0; kx < 3; ++kx) {
        const float* trow = tile + ((ly + ky) * TP + (lx + kx)) * CP;
#pragma unroll
        for (int i4 = 0; i4 < 8; ++i4) {
            float vv[4];
            *(float4*)vv = *(const float4*)(trow + i4 * 4);   // ds_read_b128
#pragma unroll
            for (int j = 0; j < 4; ++j) {
                int i = i4 * 4 + j;
                const float4* w4 = (const float4*)(wt + ((i * 3 + ky) * 3 + kx) * C); // uniform
                float vj = vv[j];
#pragma unroll
                for (int o4 = 0; o4 < 8; ++o4) {
                    float4 w = w4[o4];
                    acc[o4*4+0] = fmaf(vj, w.x, acc[o4*4+0]);
                    acc[o4*4+1] = fmaf(vj, w.y, acc[o4*4+1]);
                    acc[o4*4+2] = fmaf(vj, w.z, acc[o4*4+2]);
                    acc[o4*4+3] = fmaf(vj, w.w, acc[o4*4+3]);
                }
            }
        }
    }

    // epilogue: f_hat = 0.5*h + 0.5*(conv+b); out write + loss partial
    int y = y0 + ly, x = x0 + lx;
    const float* center = tile + ((ly + 1) * TP + (lx + 1)) * CP;
    float ls = 0.f;
#pragma unroll
    for (int o = 0; o < C; ++o) {
        float fh = 0.5f * center[o] + 0.5f * acc[o];
        int oi = ((b * C + o) * HH + y) * WW + x;
        out[oi] = fh;
        float e = fh - f[oi];
        ls = fmaf(e, e, ls);
    }

    red[tid] = ls;
    __syncthreads();
    for (int s = 128; s > 0; s >>= 1) {
        if (tid < s) red[tid] += red[tid + s];
        __syncthreads();
    }
    if (tid == 0) partial[blk] = red[0];
}

// ---- final loss reduce ----
__global__ void k_final(const float* __restrict__ partial, float* __restrict__ out_loss) {
    __shared__ float red[256];
    int tid = threadIdx.x;
    red[tid] = partial[tid];
    __syncthreads();
    for (int s = 128; s > 0; s >>= 1) {
        if (tid < s) red[tid] += red[tid + s];
        __syncthreads();
    }
    if (tid == 0) out_loss[0] = 1.25f * red[0] / 2097152.0f;
}

extern "C" void kernel_launch(void* const* d_in, const int* in_sizes, int n_in,
                              void* d_out, int out_size, void* d_ws, size_t ws_size,
                              hipStream_t stream) {
    const float* f   = (const float*)d_in[0];
    const float* emb = (const float*)d_in[1];
    const float* cw  = (const float*)d_in[2];
    const float* cb  = (const float*)d_in[3];
    float* out = (float*)d_out;

    float* en      = (float*)d_ws;           // 4096 f
    float* wt      = en + V;                 // 9216 f
    int*   idx     = (int*)(wt + C * C * 9); // 65536 i
    float* partial = (float*)(idx + NPTS);   // 256 f

    k_en<<<V / 256, 256, 0, stream>>>(emb, en);
    k_wt<<<(C * C * 9 + 255) / 256, 256, 0, stream>>>(cw, wt);
    k_argmin<<<NPTS / 256, 256, 0, stream>>>(f, emb, en, idx);
    k_conv<<<256, 256, 0, stream>>>(f, emb, idx, wt, cb, out, partial);
    k_final<<<1, 256, 0, stream>>>(partial, out + 2097152);
}

// Round 2
// 439.958 us; speedup vs baseline: 3.9530x; 3.9530x over previous
//
#include <hip/hip_runtime.h>

#define NPTS 65536
#define V 4096
#define C 32
#define HH 64
#define WW 64

#define VCH 256      // codes per chunk
#define NCH 16       // V / VCH

#define TS 16
#define TP 18        // tile + halo
#define CP 36        // padded channel stride (floats)

__device__ inline unsigned int ford(float d) {
    unsigned int b = __float_as_uint(d);
    return (b & 0x80000000u) ? ~b : (b | 0x80000000u);   // monotonic uint order
}

// ---- init packed argmin keys to +inf ----
__global__ void k_init(unsigned long long* __restrict__ key) {
    key[blockIdx.x * 256 + threadIdx.x] = ~0ULL;
}

// ---- 0.5*||e_v||^2 ----
__global__ void k_en(const float* __restrict__ emb, float* __restrict__ en) {
    int v = blockIdx.x * 256 + threadIdx.x;
    const float4* e4 = (const float4*)(emb + v * C);
    float s = 0.f;
#pragma unroll
    for (int j = 0; j < 8; ++j) {
        float4 q = e4[j];
        s += q.x*q.x + q.y*q.y + q.z*q.z + q.w*q.w;
    }
    en[v] = 0.5f * s;
}

// ---- transpose conv weights OIHW -> [i][ky][kx][o] ----
__global__ void k_wt(const float* __restrict__ cw, float* __restrict__ wt) {
    int t = blockIdx.x * 256 + threadIdx.x;
    if (t >= C * C * 9) return;
    int o = t & 31;
    int r = t >> 5;
    int kx = r % 3;
    int ky = (r / 3) % 3;
    int i  = r / 9;
    wt[t] = cw[((o * C + i) * 3 + ky) * 3 + kx];
}

// ---- nearest-code partial argmin over one V-chunk; merge via u64 atomicMin ----
__global__ __launch_bounds__(256) void k_argmin2(const float* __restrict__ f,
                                                 const float* __restrict__ emb,
                                                 const float* __restrict__ en,
                                                 unsigned long long* __restrict__ key) {
    int blk = blockIdx.x;
    int ci = blk & (NCH - 1);
    int pb = blk >> 4;
    int n = pb * 256 + threadIdx.x;
    int b = n >> 12, pix = n & 4095;

    float x[C];
#pragma unroll
    for (int c = 0; c < C; ++c) x[c] = f[(b * C + c) * 4096 + pix];

    const float* ech  = emb + (size_t)ci * VCH * C;   // wave-uniform rows -> s_load
    const float* ench = en + ci * VCH;

    float best = 3.4e38f;
    int bi = 0;
#pragma unroll 4
    for (int v = 0; v < VCH; ++v) {
        const float4* e4 = (const float4*)(ech + v * C);
        float d0 = ench[v], d1 = 0.f;
#pragma unroll
        for (int j = 0; j < 4; ++j) {
            float4 q = e4[j];
            d0 = fmaf(q.x, -x[4*j+0], d0);
            d0 = fmaf(q.y, -x[4*j+1], d0);
            d0 = fmaf(q.z, -x[4*j+2], d0);
            d0 = fmaf(q.w, -x[4*j+3], d0);
        }
#pragma unroll
        for (int j = 4; j < 8; ++j) {
            float4 q = e4[j];
            d1 = fmaf(q.x, -x[4*j+0], d1);
            d1 = fmaf(q.y, -x[4*j+1], d1);
            d1 = fmaf(q.z, -x[4*j+2], d1);
            d1 = fmaf(q.w, -x[4*j+3], d1);
        }
        float d = d0 + d1;
        if (d < best) { best = d; bi = v; }   // strict <: lowest v wins in-chunk
    }
    unsigned long long k = ((unsigned long long)ford(best) << 32)
                         | (unsigned int)(ci * VCH + bi);
    atomicMin(&key[n], k);                     // cross-chunk: min d, tie -> min v
}

// ---- fused gather + conv3x3 + Phi + output + loss partials ----
__global__ __launch_bounds__(256) void k_conv(const float* __restrict__ f,
                                              const float* __restrict__ emb,
                                              const unsigned long long* __restrict__ key,
                                              const float* __restrict__ wt,
                                              const float* __restrict__ cb,
                                              float* __restrict__ out,
                                              float* __restrict__ partial) {
    __shared__ float tile[TP * TP * CP];
    __shared__ float red[256];

    int blk = blockIdx.x;
    int b = blk >> 4, t = blk & 15;
    int y0 = (t >> 2) * TS, x0 = (t & 3) * TS;
    int tid = threadIdx.x;

    for (int p = tid; p < TP * TP; p += 256) {
        int gy = y0 + (p / TP) - 1;
        int gx = x0 + (p % TP) - 1;
        float4 e[8];
        if (gy >= 0 && gy < HH && gx >= 0 && gx < WW) {
            int id = (int)(key[b * 4096 + gy * WW + gx] & 0xFFFFu);
            const float4* e4 = (const float4*)(emb + id * C);
#pragma unroll
            for (int j = 0; j < 8; ++j) e[j] = e4[j];
        } else {
#pragma unroll
            for (int j = 0; j < 8; ++j) e[j] = make_float4(0.f, 0.f, 0.f, 0.f);
        }
        float4* dst = (float4*)(tile + p * CP);
#pragma unroll
        for (int j = 0; j < 8; ++j) dst[j] = e[j];
    }
    __syncthreads();

    int ly = tid >> 4, lx = tid & 15;
    float acc[C];
#pragma unroll
    for (int o = 0; o < C; ++o) acc[o] = cb[o];

#pragma unroll
    for (int ky = 0; ky < 3; ++ky)
#pragma unroll
    for (int kx = 0; kx < 3; ++kx) {
        const float* trow = tile + ((ly + ky) * TP + (lx + kx)) * CP;
#pragma unroll
        for (int i4 = 0; i4 < 8; ++i4) {
            float vv[4];
            *(float4*)vv = *(const float4*)(trow + i4 * 4);
#pragma unroll
            for (int j = 0; j < 4; ++j) {
                int i = i4 * 4 + j;
                const float4* w4 = (const float4*)(wt + ((i * 3 + ky) * 3 + kx) * C);
                float vj = vv[j];
#pragma unroll
                for (int o4 = 0; o4 < 8; ++o4) {
                    float4 w = w4[o4];
                    acc[o4*4+0] = fmaf(vj, w.x, acc[o4*4+0]);
                    acc[o4*4+1] = fmaf(vj, w.y, acc[o4*4+1]);
                    acc[o4*4+2] = fmaf(vj, w.z, acc[o4*4+2]);
                    acc[o4*4+3] = fmaf(vj, w.w, acc[o4*4+3]);
                }
            }
        }
    }

    int y = y0 + ly, x = x0 + lx;
    const float* center = tile + ((ly + 1) * TP + (lx + 1)) * CP;
    float ls = 0.f;
#pragma unroll
    for (int o = 0; o < C; ++o) {
        float fh = 0.5f * center[o] + 0.5f * acc[o];
        int oi = ((b * C + o) * HH + y) * WW + x;
        out[oi] = fh;
        float e = fh - f[oi];
        ls = fmaf(e, e, ls);
    }

    red[tid] = ls;
    __syncthreads();
    for (int s = 128; s > 0; s >>= 1) {
        if (tid < s) red[tid] += red[tid + s];
        __syncthreads();
    }
    if (tid == 0) partial[blk] = red[0];
}

// ---- final loss reduce ----
__global__ void k_final(const float* __restrict__ partial, float* __restrict__ out_loss) {
    __shared__ float red[256];
    int tid = threadIdx.x;
    red[tid] = partial[tid];
    __syncthreads();
    for (int s = 128; s > 0; s >>= 1) {
        if (tid < s) red[tid] += red[tid + s];
        __syncthreads();
    }
    if (tid == 0) out_loss[0] = 1.25f * red[0] / 2097152.0f;
}

extern "C" void kernel_launch(void* const* d_in, const int* in_sizes, int n_in,
                              void* d_out, int out_size, void* d_ws, size_t ws_size,
                              hipStream_t stream) {
    const float* f   = (const float*)d_in[0];
    const float* emb = (const float*)d_in[1];
    const float* cw  = (const float*)d_in[2];
    const float* cb  = (const float*)d_in[3];
    float* out = (float*)d_out;

    unsigned long long* keyb = (unsigned long long*)d_ws;     // 65536 * 8B
    float* en      = (float*)(keyb + NPTS);                   // 4096 f
    float* wt      = en + V;                                  // 9216 f
    float* partial = wt + C * C * 9;                          // 256 f

    k_init<<<NPTS / 256, 256, 0, stream>>>(keyb);
    k_en<<<V / 256, 256, 0, stream>>>(emb, en);
    k_wt<<<(C * C * 9 + 255) / 256, 256, 0, stream>>>(cw, wt);
    k_argmin2<<<NPTS / 256 * NCH, 256, 0, stream>>>(f, emb, en, keyb);
    k_conv<<<256, 256, 0, stream>>>(f, emb, keyb, wt, cb, out, partial);
    k_final<<<1, 256, 0, stream>>>(partial, out + 2097152);
}

// Round 3
// 237.170 us; speedup vs baseline: 7.3330x; 1.8550x over previous
//
#include <hip/hip_runtime.h>

#define NPTS 65536
#define V 4096
#define C 32
#define HH 64
#define WW 64

#define TS 16
#define TP 18
#define CP 36

#define MARG 8e-3f   // 2*eps margin for coarse bf16x3 argmin acceptance

typedef short bf8 __attribute__((ext_vector_type(8)));   // 8 bf16 in 4 VGPRs
typedef float f4 __attribute__((ext_vector_type(4)));

__device__ inline unsigned int ford(float d) {
    unsigned int b = __float_as_uint(d);
    return (b & 0x80000000u) ? ~b : (b | 0x80000000u);
}

__device__ inline short bf16rne(float x) {
    unsigned u = __float_as_uint(x);
    unsigned hb = (u + 0x7FFFu + ((u >> 16) & 1u)) & 0xFFFF0000u;
    return (short)(hb >> 16);
}
__device__ inline float bf16rne_f(float x, short* s) {
    unsigned u = __float_as_uint(x);
    unsigned hb = (u + 0x7FFFu + ((u >> 16) & 1u)) & 0xFFFF0000u;
    *s = (short)(hb >> 16);
    return __uint_as_float(hb);
}

// ---- zero flag counter ----
__global__ void k_init0(int* __restrict__ cnt) { if (threadIdx.x == 0) cnt[0] = 0; }

// ---- 0.5*||e_v||^2 ----
__global__ void k_en(const float* __restrict__ emb, float* __restrict__ en) {
    int v = blockIdx.x * 256 + threadIdx.x;
    const float4* e4 = (const float4*)(emb + v * C);
    float s = 0.f;
#pragma unroll
    for (int j = 0; j < 8; ++j) {
        float4 q = e4[j];
        s += q.x*q.x + q.y*q.y + q.z*q.z + q.w*q.w;
    }
    en[v] = 0.5f * s;
}

// ---- conv weights OIHW -> [i][ky][kx][o] ----
__global__ void k_wt(const float* __restrict__ cw, float* __restrict__ wt) {
    int t = blockIdx.x * 256 + threadIdx.x;
    if (t >= C * C * 9) return;
    int o = t & 31;
    int r = t >> 5;
    int kx = r % 3;
    int ky = (r / 3) % 3;
    int i  = r / 9;
    wt[t] = cw[((o * C + i) * 3 + ky) * 3 + kx];
}

// ---- codebook -> bf16 hi/lo MFMA B-fragments: EH/EL[vt*64+lane] ----
__global__ void k_prep_e(const float* __restrict__ emb, bf8* __restrict__ EH,
                         bf8* __restrict__ EL) {
    int gid = blockIdx.x * 256 + threadIdx.x;      // 16384 = 256 vt * 64 lanes
    int vt = gid >> 6, lane = gid & 63;
    int col = lane & 15, k0 = (lane >> 4) * 8;
    const float* e = emb + (vt * 16 + col) * C + k0;
    bf8 h, l;
#pragma unroll
    for (int j = 0; j < 8; ++j) {
        short hs;
        float hf = bf16rne_f(e[j], &hs);
        h[j] = hs;
        l[j] = bf16rne(e[j] - hf);
    }
    EH[gid] = h;
    EL[gid] = l;
}

// ---- MFMA coarse argmin + ambiguity flagging ----
__global__ __launch_bounds__(256) void k_argmfma(const float* __restrict__ f,
        const bf8* __restrict__ EH, const bf8* __restrict__ EL,
        const float* __restrict__ en, int* __restrict__ idx,
        int* __restrict__ cnt, int* __restrict__ flags,
        unsigned long long* __restrict__ fkey) {
    __shared__ bf8 sEH[1024];
    __shared__ bf8 sEL[1024];
    __shared__ float sen[256];

    int tid = threadIdx.x;
    int lane = tid & 63;
    int wv = tid >> 6;
    int tile = blockIdx.x * 4 + wv;
    int row = lane & 15, kb = lane >> 4;
    int n = tile * 16 + row;
    int b = n >> 12, pix = n & 4095;

    // load x (8 channels per lane) and split hi/lo
    bf8 xh, xl;
    const float* fp = f + ((size_t)b * C + kb * 8) * 4096 + pix;
#pragma unroll
    for (int j = 0; j < 8; ++j) {
        float x = fp[(size_t)j * 4096];
        short hs;
        float hf = bf16rne_f(x, &hs);
        xh[j] = hs;
        xl[j] = bf16rne(x - hf);
    }

    float best[4], best2[4];
    int vb[4];
#pragma unroll
    for (int r = 0; r < 4; ++r) { best[r] = -3.4e38f; best2[r] = -3.4e38f; vb[r] = 0; }

    for (int c = 0; c < 16; ++c) {
        if (c) __syncthreads();
#pragma unroll
        for (int q = 0; q < 4; ++q) {
            int o = q * 256 + tid;
            sEH[o] = EH[c * 1024 + o];
            sEL[o] = EL[c * 1024 + o];
        }
        sen[tid] = en[c * 256 + tid];
        __syncthreads();
#pragma unroll
        for (int s = 0; s < 16; ++s) {
            bf8 eh = sEH[s * 64 + lane];
            bf8 el = sEL[s * 64 + lane];
            float negen = -sen[s * 16 + (lane & 15)];
            f4 acc = {negen, negen, negen, negen};
            acc = __builtin_amdgcn_mfma_f32_16x16x32_bf16(xh, eh, acc, 0, 0, 0);
            acc = __builtin_amdgcn_mfma_f32_16x16x32_bf16(xh, el, acc, 0, 0, 0);
            acc = __builtin_amdgcn_mfma_f32_16x16x32_bf16(xl, eh, acc, 0, 0, 0);
            int vt = c * 16 + s;
#pragma unroll
            for (int r = 0; r < 4; ++r) {
                float sv = acc[r];                       // s = x.e - en  (maximize)
                best2[r] = fmaxf(best2[r], fminf(best[r], sv));
                bool g = sv > best[r];
                best[r] = fmaxf(best[r], sv);
                vb[r] = g ? vt : vb[r];
            }
        }
    }

    // 16-lane (code-column) merge per point
    int col = lane & 15;
#pragma unroll
    for (int r = 0; r < 4; ++r) {
        float bb = best[r], b2 = best2[r];
        int vv = vb[r] * 16 + col;
#pragma unroll
        for (int m = 1; m < 16; m <<= 1) {
            float ob  = __shfl_xor(bb, m);
            float ob2 = __shfl_xor(b2, m);
            int   ov  = __shfl_xor(vv, m);
            b2 = fmaxf(fminf(bb, ob), fmaxf(b2, ob2));
            bool take = (ob > bb) || (ob == bb && ov < vv);
            vv = take ? ov : vv;
            bb = fmaxf(bb, ob);
        }
        if (col == 0) {
            int nn = tile * 16 + kb * 4 + r;
            idx[nn] = vv;
            if (bb - b2 <= MARG) {            // ambiguous: exact fp32 recheck
                int pos = atomicAdd(cnt, 1);
                flags[pos] = nn;
                fkey[pos] = ~0ULL;
            }
        }
    }
}

// ---- exact fp32 recheck for flagged points (64 code-chunks per point) ----
__global__ __launch_bounds__(256) void k_exact(const float* __restrict__ f,
        const float* __restrict__ emb, const float* __restrict__ en,
        const int* __restrict__ cnt, const int* __restrict__ flags,
        unsigned long long* __restrict__ fkey) {
    int total = cnt[0] * 64;
    for (int t = blockIdx.x * 256 + threadIdx.x; t < total; t += gridDim.x * 256) {
        int fi = t >> 6, ch = t & 63;
        int n = flags[fi];
        int b = n >> 12, pix = n & 4095;
        float x[C];
#pragma unroll
        for (int c = 0; c < C; ++c) x[c] = f[((size_t)b * C + c) * 4096 + pix];
        float bd = 3.4e38f;
        int bv = 0;
        const float* eb = emb + ch * 64 * C;
        const float* enb = en + ch * 64;
        for (int v2 = 0; v2 < 64; ++v2) {
            const float4* e4 = (const float4*)(eb + v2 * C);
            float d0 = enb[v2], d1 = 0.f;
#pragma unroll
            for (int j = 0; j < 4; ++j) {
                float4 q = e4[j];
                d0 = fmaf(q.x, -x[4*j+0], d0);
                d0 = fmaf(q.y, -x[4*j+1], d0);
                d0 = fmaf(q.z, -x[4*j+2], d0);
                d0 = fmaf(q.w, -x[4*j+3], d0);
            }
#pragma unroll
            for (int j = 4; j < 8; ++j) {
                float4 q = e4[j];
                d1 = fmaf(q.x, -x[4*j+0], d1);
                d1 = fmaf(q.y, -x[4*j+1], d1);
                d1 = fmaf(q.z, -x[4*j+2], d1);
                d1 = fmaf(q.w, -x[4*j+3], d1);
            }
            float d = d0 + d1;
            if (d < bd) { bd = d; bv = ch * 64 + v2; }
        }
        unsigned long long k = ((unsigned long long)ford(bd) << 32) | (unsigned int)bv;
        atomicMin(&fkey[fi], k);
    }
}

// ---- apply exact results ----
__global__ void k_fix(const int* __restrict__ cnt, const int* __restrict__ flags,
                      const unsigned long long* __restrict__ fkey, int* __restrict__ idx) {
    int t = blockIdx.x * 256 + threadIdx.x;
    if (t < cnt[0]) idx[flags[t]] = (int)(fkey[t] & 0xFFFFu);
}

// ---- fused gather + conv3x3 + Phi + output + loss partials ----
__global__ __launch_bounds__(256) void k_conv(const float* __restrict__ f,
                                              const float* __restrict__ emb,
                                              const int* __restrict__ idx,
                                              const float* __restrict__ wt,
                                              const float* __restrict__ cb,
                                              float* __restrict__ out,
                                              float* __restrict__ partial) {
    __shared__ float tile[TP * TP * CP];
    __shared__ float red[256];

    int blk = blockIdx.x;
    int b = blk >> 4, t = blk & 15;
    int y0 = (t >> 2) * TS, x0 = (t & 3) * TS;
    int tid = threadIdx.x;

    for (int p = tid; p < TP * TP; p += 256) {
        int gy = y0 + (p / TP) - 1;
        int gx = x0 + (p % TP) - 1;
        float4 e[8];
        if (gy >= 0 && gy < HH && gx >= 0 && gx < WW) {
            int id = idx[b * 4096 + gy * WW + gx];
            const float4* e4 = (const float4*)(emb + id * C);
#pragma unroll
            for (int j = 0; j < 8; ++j) e[j] = e4[j];
        } else {
#pragma unroll
            for (int j = 0; j < 8; ++j) e[j] = make_float4(0.f, 0.f, 0.f, 0.f);
        }
        float4* dst = (float4*)(tile + p * CP);
#pragma unroll
        for (int j = 0; j < 8; ++j) dst[j] = e[j];
    }
    __syncthreads();

    int ly = tid >> 4, lx = tid & 15;
    float acc[C];
#pragma unroll
    for (int o = 0; o < C; ++o) acc[o] = cb[o];

#pragma unroll
    for (int ky = 0; ky < 3; ++ky)
#pragma unroll
    for (int kx = 0; kx < 3; ++kx) {
        const float* trow = tile + ((ly + ky) * TP + (lx + kx)) * CP;
#pragma unroll
        for (int i4 = 0; i4 < 8; ++i4) {
            float vv[4];
            *(float4*)vv = *(const float4*)(trow + i4 * 4);
#pragma unroll
            for (int j = 0; j < 4; ++j) {
                int i = i4 * 4 + j;
                const float4* w4 = (const float4*)(wt + ((i * 3 + ky) * 3 + kx) * C);
                float vj = vv[j];
#pragma unroll
                for (int o4 = 0; o4 < 8; ++o4) {
                    float4 w = w4[o4];
                    acc[o4*4+0] = fmaf(vj, w.x, acc[o4*4+0]);
                    acc[o4*4+1] = fmaf(vj, w.y, acc[o4*4+1]);
                    acc[o4*4+2] = fmaf(vj, w.z, acc[o4*4+2]);
                    acc[o4*4+3] = fmaf(vj, w.w, acc[o4*4+3]);
                }
            }
        }
    }

    int y = y0 + ly, x = x0 + lx;
    const float* center = tile + ((ly + 1) * TP + (lx + 1)) * CP;
    float ls = 0.f;
#pragma unroll
    for (int o = 0; o < C; ++o) {
        float fh = 0.5f * center[o] + 0.5f * acc[o];
        int oi = ((b * C + o) * HH + y) * WW + x;
        out[oi] = fh;
        float e = fh - f[oi];
        ls = fmaf(e, e, ls);
    }

    red[tid] = ls;
    __syncthreads();
    for (int s = 128; s > 0; s >>= 1) {
        if (tid < s) red[tid] += red[tid + s];
        __syncthreads();
    }
    if (tid == 0) partial[blk] = red[0];
}

__global__ void k_final(const float* __restrict__ partial, float* __restrict__ out_loss) {
    __shared__ float red[256];
    int tid = threadIdx.x;
    red[tid] = partial[tid];
    __syncthreads();
    for (int s = 128; s > 0; s >>= 1) {
        if (tid < s) red[tid] += red[tid + s];
        __syncthreads();
    }
    if (tid == 0) out_loss[0] = 1.25f * red[0] / 2097152.0f;
}

extern "C" void kernel_launch(void* const* d_in, const int* in_sizes, int n_in,
                              void* d_out, int out_size, void* d_ws, size_t ws_size,
                              hipStream_t stream) {
    const float* f   = (const float*)d_in[0];
    const float* emb = (const float*)d_in[1];
    const float* cw  = (const float*)d_in[2];
    const float* cb  = (const float*)d_in[3];
    float* out = (float*)d_out;

    char* w = (char*)d_ws;
    float* en      = (float*)w;                 w += V * 4;            // 16KB
    float* wt      = (float*)w;                 w += C * C * 9 * 4;    // 36KB
    int*   idx     = (int*)w;                   w += NPTS * 4;         // 256KB
    int*   flags   = (int*)w;                   w += NPTS * 4;         // 256KB
    unsigned long long* fkey = (unsigned long long*)w; w += NPTS * 8;  // 512KB
    int*   cnt     = (int*)w;                   w += 256;
    float* partial = (float*)w;                 w += 256 * 4;
    bf8*   EH      = (bf8*)w;                   w += 256 * 64 * 16;    // 256KB
    bf8*   EL      = (bf8*)w;                   w += 256 * 64 * 16;    // 256KB

    k_init0<<<1, 64, 0, stream>>>(cnt);
    k_en<<<V / 256, 256, 0, stream>>>(emb, en);
    k_wt<<<(C * C * 9 + 255) / 256, 256, 0, stream>>>(cw, wt);
    k_prep_e<<<64, 256, 0, stream>>>(emb, EH, EL);
    k_argmfma<<<NPTS / 16 / 4, 256, 0, stream>>>(f, EH, EL, en, idx, cnt, flags, fkey);
    k_exact<<<1024, 256, 0, stream>>>(f, emb, en, cnt, flags, fkey);
    k_fix<<<NPTS / 256, 256, 0, stream>>>(cnt, flags, fkey, idx);
    k_conv<<<256, 256, 0, stream>>>(f, emb, idx, wt, cb, out, partial);
    k_final<<<1, 256, 0, stream>>>(partial, out + 2097152);
}

// Round 4
// 197.852 us; speedup vs baseline: 8.7903x; 1.1987x over previous
//
#include <hip/hip_runtime.h>

#define NPTS 65536
#define V 4096
#define C 32
#define HH 64
#define WW 64
#define NSPLIT 4
#define MARG 1.0e-2f

typedef short bf8 __attribute__((ext_vector_type(8)));   // 8 bf16 in 4 VGPRs
typedef float f4 __attribute__((ext_vector_type(4)));

__device__ inline unsigned int ford(float d) {
    unsigned int b = __float_as_uint(d);
    return (b & 0x80000000u) ? ~b : (b | 0x80000000u);
}
__device__ inline short bf16rne(float x) {
    unsigned u = __float_as_uint(x);
    unsigned hb = (u + 0x7FFFu + ((u >> 16) & 1u)) & 0xFFFF0000u;
    return (short)(hb >> 16);
}
__device__ inline float bf16rne_f(float x, short* s) {
    unsigned u = __float_as_uint(x);
    unsigned hb = (u + 0x7FFFu + ((u >> 16) & 1u)) & 0xFFFF0000u;
    *s = (short)(hb >> 16);
    return __uint_as_float(hb);
}

__global__ void k_init0(int* __restrict__ cnt) { if (threadIdx.x == 0) cnt[0] = 0; }

// ---- enneg[v] = -0.5*||e_v||^2 ----
__global__ void k_en(const float* __restrict__ emb, float* __restrict__ enneg) {
    int v = blockIdx.x * 256 + threadIdx.x;
    const float4* e4 = (const float4*)(emb + v * C);
    float s = 0.f;
#pragma unroll
    for (int j = 0; j < 8; ++j) {
        float4 q = e4[j];
        s += q.x*q.x + q.y*q.y + q.z*q.z + q.w*q.w;
    }
    enneg[v] = -0.5f * s;
}

// ---- conv weights OIHW -> [i][ky][kx][o] ----
__global__ void k_wt(const float* __restrict__ cw, float* __restrict__ wt) {
    int t = blockIdx.x * 256 + threadIdx.x;
    if (t >= C * C * 9) return;
    int o = t & 31;
    int r = t >> 5;
    int kx = r % 3;
    int ky = (r / 3) % 3;
    int i  = r / 9;
    wt[t] = cw[((o * C + i) * 3 + ky) * 3 + kx];
}

// ---- codebook -> bf16 hi/lo MFMA B-fragments: EH/EL[vt*64+lane] ----
__global__ void k_prep_e(const float* __restrict__ emb, bf8* __restrict__ EH,
                         bf8* __restrict__ EL) {
    int gid = blockIdx.x * 256 + threadIdx.x;      // 16384 = 256 vt * 64 lanes
    int vt = gid >> 6, lane = gid & 63;
    int col = lane & 15, k0 = (lane >> 4) * 8;
    const float* e = emb + (vt * 16 + col) * C + k0;
    bf8 h, l;
#pragma unroll
    for (int j = 0; j < 8; ++j) {
        short hs;
        float hf = bf16rne_f(e[j], &hs);
        h[j] = hs;
        l[j] = bf16rne(e[j] - hf);
    }
    EH[gid] = h;
    EL[gid] = l;
}

// ---- MFMA coarse argmin: 64 points/wave (4 tiles), 1024 codes/block (split 4) ----
__global__ __launch_bounds__(256, 3) void k_argmfma(const float* __restrict__ f,
        const bf8* __restrict__ EH, const bf8* __restrict__ EL,
        const float* __restrict__ enneg, float* __restrict__ bvv,
        float* __restrict__ b2a, int* __restrict__ iva) {
    __shared__ bf8 sEH[1024];
    __shared__ bf8 sEL[1024];
    __shared__ float sen[256];

    int tid = threadIdx.x;
    int lane = tid & 63;
    int wv = tid >> 6;
    int ci = blockIdx.x >> 8;        // code split 0..3 (1024 codes each)
    int pb = blockIdx.x & 255;       // point block (256 points)
    int base = pb * 256 + wv * 64;
    int row = lane & 15, kb = lane >> 4;

    // x fragments, hi/lo bf16 split
    bf8 xh[4], xl[4];
#pragma unroll
    for (int t = 0; t < 4; ++t) {
        int n = base + t * 16 + row;
        int b = n >> 12, pix = n & 4095;
        const float* fp = f + ((size_t)(b * C + kb * 8)) * 4096 + pix;
#pragma unroll
        for (int j = 0; j < 8; ++j) {
            float x = fp[(size_t)j * 4096];
            short hs;
            float hf = bf16rne_f(x, &hs);
            xh[t][j] = hs;
            xl[t][j] = bf16rne(x - hf);
        }
    }

    float best[16], best2[16];
#pragma unroll
    for (int e = 0; e < 16; ++e) { best[e] = -3.4e38f; best2[e] = -3.4e38f; }

    for (int ph = 0; ph < 4; ++ph) {
        if (ph) __syncthreads();
        int off = ci * 4096 + ph * 1024;
#pragma unroll
        for (int q = 0; q < 4; ++q) {
            sEH[q * 256 + tid] = EH[off + q * 256 + tid];
            sEL[q * 256 + tid] = EL[off + q * 256 + tid];
        }
        sen[tid] = enneg[ci * 1024 + ph * 256 + tid];
        __syncthreads();
#pragma unroll
        for (int s2 = 0; s2 < 8; ++s2) {
            float k1[16], k2[16];
            {
                int s = 2 * s2;
                bf8 eh = sEH[s * 64 + lane];
                bf8 el = sEL[s * 64 + lane];
                float ng = sen[s * 16 + row];
                unsigned vtb = 63u - (unsigned)(ph * 16 + s);
#pragma unroll
                for (int t = 0; t < 4; ++t) {
                    f4 acc = {ng, ng, ng, ng};
                    acc = __builtin_amdgcn_mfma_f32_16x16x32_bf16(xh[t], eh, acc, 0, 0, 0);
                    acc = __builtin_amdgcn_mfma_f32_16x16x32_bf16(xh[t], el, acc, 0, 0, 0);
                    acc = __builtin_amdgcn_mfma_f32_16x16x32_bf16(xl[t], eh, acc, 0, 0, 0);
#pragma unroll
                    for (int r = 0; r < 4; ++r)
                        k1[t*4+r] = __uint_as_float((__float_as_uint(acc[r]) & 0xFFFFFFC0u) | vtb);
                }
            }
            {
                int s = 2 * s2 + 1;
                bf8 eh = sEH[s * 64 + lane];
                bf8 el = sEL[s * 64 + lane];
                float ng = sen[s * 16 + row];
                unsigned vtb = 63u - (unsigned)(ph * 16 + s);
#pragma unroll
                for (int t = 0; t < 4; ++t) {
                    f4 acc = {ng, ng, ng, ng};
                    acc = __builtin_amdgcn_mfma_f32_16x16x32_bf16(xh[t], eh, acc, 0, 0, 0);
                    acc = __builtin_amdgcn_mfma_f32_16x16x32_bf16(xh[t], el, acc, 0, 0, 0);
                    acc = __builtin_amdgcn_mfma_f32_16x16x32_bf16(xl[t], eh, acc, 0, 0, 0);
#pragma unroll
                    for (int r = 0; r < 4; ++r)
                        k2[t*4+r] = __uint_as_float((__float_as_uint(acc[r]) & 0xFFFFFFC0u) | vtb);
                }
            }
#pragma unroll
            for (int e = 0; e < 16; ++e) {
                float m = __builtin_amdgcn_fmed3f(best[e], k1[e], k2[e]); // 2nd of {best,k1,k2}
                best2[e] = fmaxf(best2[e], m);
                best[e] = fmaxf(fmaxf(best[e], k1[e]), k2[e]);
            }
        }
    }

    // decode + 16-col merge + per-split write
#pragma unroll
    for (int t = 0; t < 4; ++t) {
#pragma unroll
        for (int r = 0; r < 4; ++r) {
            float bb = best[t*4+r], b2 = best2[t*4+r];
            int ii = (ci * 64 + 63 - (int)(__float_as_uint(bb) & 63u)) * 16 + row;
#pragma unroll
            for (int m = 1; m < 16; m <<= 1) {
                float ob  = __shfl_xor(bb, m);
                float ob2 = __shfl_xor(b2, m);
                int   oi  = __shfl_xor(ii, m);
                b2 = fmaxf(fmaxf(b2, ob2), fminf(bb, ob));
                bool take = (ob > bb) || (ob == bb && oi < ii);
                ii = take ? oi : ii;
                bb = fmaxf(bb, ob);
            }
            if (row == 0) {
                int p = base + t * 16 + kb * 4 + r;
                int o = ci * NPTS + p;
                bvv[o] = bb; b2a[o] = b2; iva[o] = ii;
            }
        }
    }
}

// ---- merge 4 splits, write idx, flag ambiguous ----
__global__ void k_merge(const float* __restrict__ bvv, const float* __restrict__ b2a,
                        const int* __restrict__ iva, int* __restrict__ idx,
                        int* __restrict__ cnt, int* __restrict__ flags,
                        unsigned long long* __restrict__ fkey) {
    int n = blockIdx.x * 256 + threadIdx.x;
    float bb = bvv[n], b2 = b2a[n];
    int ii = iva[n];
#pragma unroll
    for (int s = 1; s < NSPLIT; ++s) {
        float ob  = bvv[s * NPTS + n];
        float ob2 = b2a[s * NPTS + n];
        int   oi  = iva[s * NPTS + n];
        b2 = fmaxf(fmaxf(b2, ob2), fminf(bb, ob));
        bool take = (ob > bb) || (ob == bb && oi < ii);
        ii = take ? oi : ii;
        bb = fmaxf(bb, ob);
    }
    idx[n] = ii;
    if (bb - b2 <= MARG) {
        int pos = atomicAdd(cnt, 1);
        flags[pos] = n;
        fkey[pos] = ~0ULL;
    }
}

// ---- exact fp32 recheck for flagged points ----
__global__ __launch_bounds__(256) void k_exact(const float* __restrict__ f,
        const float* __restrict__ emb, const float* __restrict__ enneg,
        const int* __restrict__ cnt, const int* __restrict__ flags,
        unsigned long long* __restrict__ fkey) {
    int total = cnt[0] * 64;
    for (int t = blockIdx.x * 256 + threadIdx.x; t < total; t += gridDim.x * 256) {
        int fi = t >> 6, ch = t & 63;
        int n = flags[fi];
        int b = n >> 12, pix = n & 4095;
        float x[C];
#pragma unroll
        for (int c = 0; c < C; ++c) x[c] = f[((size_t)b * C + c) * 4096 + pix];
        float bd = 3.4e38f;
        int bv = 0;
        const float* eb = emb + ch * 64 * C;
        const float* enb = enneg + ch * 64;
        for (int v2 = 0; v2 < 64; ++v2) {
            const float4* e4 = (const float4*)(eb + v2 * C);
            float d0 = -enb[v2], d1 = 0.f;       // 0.5||e||^2 - x.e
#pragma unroll
            for (int j = 0; j < 4; ++j) {
                float4 q = e4[j];
                d0 = fmaf(q.x, -x[4*j+0], d0);
                d0 = fmaf(q.y, -x[4*j+1], d0);
                d0 = fmaf(q.z, -x[4*j+2], d0);
                d0 = fmaf(q.w, -x[4*j+3], d0);
            }
#pragma unroll
            for (int j = 4; j < 8; ++j) {
                float4 q = e4[j];
                d1 = fmaf(q.x, -x[4*j+0], d1);
                d1 = fmaf(q.y, -x[4*j+1], d1);
                d1 = fmaf(q.z, -x[4*j+2], d1);
                d1 = fmaf(q.w, -x[4*j+3], d1);
            }
            float d = d0 + d1;
            if (d < bd) { bd = d; bv = ch * 64 + v2; }
        }
        unsigned long long k = ((unsigned long long)ford(bd) << 32) | (unsigned int)bv;
        atomicMin(&fkey[fi], k);
    }
}

__global__ void k_fix(const int* __restrict__ cnt, const int* __restrict__ flags,
                      const unsigned long long* __restrict__ fkey, int* __restrict__ idx) {
    int t = blockIdx.x * 256 + threadIdx.x;
    if (t < cnt[0]) idx[flags[t]] = (int)(fkey[t] & 0xFFFFu);
}

// ---- fused gather + conv3x3 + Phi + output + loss partials (8x8 tiles, 1024 blocks) ----
__global__ __launch_bounds__(256) void k_conv(const float* __restrict__ f,
                                              const float* __restrict__ emb,
                                              const int* __restrict__ idx,
                                              const float* __restrict__ wt,
                                              const float* __restrict__ cb,
                                              float* __restrict__ out,
                                              float* __restrict__ partial) {
    __shared__ float tile[100 * 36];   // [10][10][36] padded, 14.4KB
    __shared__ float red[256];

    int blk = blockIdx.x;
    int b = blk >> 6, t = blk & 63;
    int y0 = (t >> 3) * 8, x0 = (t & 7) * 8;
    int tid = threadIdx.x;

    if (tid < 100) {
        int gy = y0 + tid / 10 - 1;
        int gx = x0 + tid % 10 - 1;
        float4 e[8];
        if (gy >= 0 && gy < HH && gx >= 0 && gx < WW) {
            int id = idx[b * 4096 + gy * WW + gx];
            const float4* e4 = (const float4*)(emb + id * C);
#pragma unroll
            for (int j = 0; j < 8; ++j) e[j] = e4[j];
        } else {
#pragma unroll
            for (int j = 0; j < 8; ++j) e[j] = make_float4(0.f, 0.f, 0.f, 0.f);
        }
        float4* dst = (float4*)(tile + tid * 36);
#pragma unroll
        for (int j = 0; j < 8; ++j) dst[j] = e[j];
    }
    __syncthreads();

    int lane = tid & 63;
    int ow = __builtin_amdgcn_readfirstlane(tid >> 6);   // wave-uniform o-block
    int px = lane & 7, py = lane >> 3;

    float acc[8];
    const float* cbp = cb + ow * 8;
#pragma unroll
    for (int j = 0; j < 8; ++j) acc[j] = cbp[j];

#pragma unroll
    for (int ky = 0; ky < 3; ++ky)
#pragma unroll
    for (int kx = 0; kx < 3; ++kx) {
        const float* trow = tile + ((py + ky) * 10 + px + kx) * 36;
#pragma unroll
        for (int i4 = 0; i4 < 8; ++i4) {
            float vv[4];
            *(float4*)vv = *(const float4*)(trow + i4 * 4);
#pragma unroll
            for (int j2 = 0; j2 < 4; ++j2) {
                int i = i4 * 4 + j2;
                const float* w8 = wt + ((i * 3 + ky) * 3 + kx) * C + ow * 8;  // uniform
                float vj = vv[j2];
#pragma unroll
                for (int o = 0; o < 8; ++o) acc[o] = fmaf(vj, w8[o], acc[o]);
            }
        }
    }

    int y = y0 + py, x = x0 + px;
    const float* center = tile + ((py + 1) * 10 + (px + 1)) * 36 + ow * 8;
    float ls = 0.f;
#pragma unroll
    for (int o = 0; o < 8; ++o) {
        float fh = 0.5f * center[o] + 0.5f * acc[o];
        int oi = ((b * C + ow * 8 + o) * HH + y) * WW + x;
        out[oi] = fh;
        float e = fh - f[oi];
        ls = fmaf(e, e, ls);
    }

    red[tid] = ls;
    __syncthreads();
    for (int s = 128; s > 0; s >>= 1) {
        if (tid < s) red[tid] += red[tid + s];
        __syncthreads();
    }
    if (tid == 0) partial[blk] = red[0];
}

// ---- final loss reduce (1024 partials) ----
__global__ void k_final(const float* __restrict__ partial, float* __restrict__ out_loss) {
    __shared__ float red[256];
    int tid = threadIdx.x;
    red[tid] = partial[tid] + partial[tid + 256] + partial[tid + 512] + partial[tid + 768];
    __syncthreads();
    for (int s = 128; s > 0; s >>= 1) {
        if (tid < s) red[tid] += red[tid + s];
        __syncthreads();
    }
    if (tid == 0) out_loss[0] = 1.25f * red[0] / 2097152.0f;
}

extern "C" void kernel_launch(void* const* d_in, const int* in_sizes, int n_in,
                              void* d_out, int out_size, void* d_ws, size_t ws_size,
                              hipStream_t stream) {
    const float* f   = (const float*)d_in[0];
    const float* emb = (const float*)d_in[1];
    const float* cw  = (const float*)d_in[2];
    const float* cb  = (const float*)d_in[3];
    float* out = (float*)d_out;

    char* w = (char*)d_ws;
    float* enneg   = (float*)w;                 w += V * 4;
    float* wt      = (float*)w;                 w += C * C * 9 * 4;
    int*   idx     = (int*)w;                   w += NPTS * 4;
    int*   flags   = (int*)w;                   w += NPTS * 4;
    unsigned long long* fkey = (unsigned long long*)w; w += NPTS * 8;
    int*   cnt     = (int*)w;                   w += 256;
    float* partial = (float*)w;                 w += 1024 * 4;
    bf8*   EH      = (bf8*)w;                   w += 256 * 64 * 16;
    bf8*   EL      = (bf8*)w;                   w += 256 * 64 * 16;
    float* bvv     = (float*)w;                 w += NSPLIT * NPTS * 4;
    float* b2a     = (float*)w;                 w += NSPLIT * NPTS * 4;
    int*   iva     = (int*)w;                   w += NSPLIT * NPTS * 4;

    k_init0<<<1, 64, 0, stream>>>(cnt);
    k_en<<<V / 256, 256, 0, stream>>>(emb, enneg);
    k_wt<<<(C * C * 9 + 255) / 256, 256, 0, stream>>>(cw, wt);
    k_prep_e<<<64, 256, 0, stream>>>(emb, EH, EL);
    k_argmfma<<<256 * NSPLIT, 256, 0, stream>>>(f, EH, EL, enneg, bvv, b2a, iva);
    k_merge<<<NPTS / 256, 256, 0, stream>>>(bvv, b2a, iva, idx, cnt, flags, fkey);
    k_exact<<<1024, 256, 0, stream>>>(f, emb, enneg, cnt, flags, fkey);
    k_fix<<<NPTS / 256, 256, 0, stream>>>(cnt, flags, fkey, idx);
    k_conv<<<1024, 256, 0, stream>>>(f, emb, idx, wt, cb, out, partial);
    k_final<<<1, 256, 0, stream>>>(partial, out + 2097152);
}

// Round 5
// 155.177 us; speedup vs baseline: 11.2076x; 1.2750x over previous
//
#include <hip/hip_runtime.h>

#define NPTS 65536
#define V 4096
#define C 32
#define HH 64
#define WW 64
#define NSPLIT 4
#define MARG 2.0e-3f

typedef short bf8 __attribute__((ext_vector_type(8)));   // 8 bf16 in 4 VGPRs
typedef float f4 __attribute__((ext_vector_type(4)));

__device__ inline unsigned int ford(float d) {
    unsigned int b = __float_as_uint(d);
    return (b & 0x80000000u) ? ~b : (b | 0x80000000u);
}
__device__ inline short bf16rne(float x) {
    unsigned u = __float_as_uint(x);
    unsigned hb = (u + 0x7FFFu + ((u >> 16) & 1u)) & 0xFFFF0000u;
    return (short)(hb >> 16);
}
__device__ inline float bf16rne_f(float x, short* s) {
    unsigned u = __float_as_uint(x);
    unsigned hb = (u + 0x7FFFu + ((u >> 16) & 1u)) & 0xFFFF0000u;
    *s = (short)(hb >> 16);
    return __uint_as_float(hb);
}

__global__ void k_init0(int* __restrict__ cnt) { if (threadIdx.x == 0) cnt[0] = 0; }

// ---- enneg[v] = -0.5*||e_v||^2 ----
__global__ void k_en(const float* __restrict__ emb, float* __restrict__ enneg) {
    int v = blockIdx.x * 256 + threadIdx.x;
    const float4* e4 = (const float4*)(emb + v * C);
    float s = 0.f;
#pragma unroll
    for (int j = 0; j < 8; ++j) {
        float4 q = e4[j];
        s += q.x*q.x + q.y*q.y + q.z*q.z + q.w*q.w;
    }
    enneg[v] = -0.5f * s;
}

// ---- conv weights OIHW -> [i][ky][kx][o] ----
__global__ void k_wt(const float* __restrict__ cw, float* __restrict__ wt) {
    int t = blockIdx.x * 256 + threadIdx.x;
    if (t >= C * C * 9) return;
    int o = t & 31;
    int r = t >> 5;
    int kx = r % 3;
    int ky = (r / 3) % 3;
    int i  = r / 9;
    wt[t] = cw[((o * C + i) * 3 + ky) * 3 + kx];
}

// ---- codebook -> bf16 hi/lo MFMA B-fragments: EH/EL[vt*64+lane] ----
__global__ void k_prep_e(const float* __restrict__ emb, bf8* __restrict__ EH,
                         bf8* __restrict__ EL) {
    int gid = blockIdx.x * 256 + threadIdx.x;      // 16384 = 256 vt * 64 lanes
    int vt = gid >> 6, lane = gid & 63;
    int col = lane & 15, k0 = (lane >> 4) * 8;
    const float* e = emb + (vt * 16 + col) * C + k0;
    bf8 h, l;
#pragma unroll
    for (int j = 0; j < 8; ++j) {
        short hs;
        float hf = bf16rne_f(e[j], &hs);
        h[j] = hs;
        l[j] = bf16rne(e[j] - hf);
    }
    EH[gid] = h;
    EL[gid] = l;
}

// ---- MFMA coarse argmin: 32 pts/wave (2 tiles), 1024 codes/split, 2048 blocks ----
__global__ __launch_bounds__(256, 4) void k_argmfma(const float* __restrict__ f,
        const bf8* __restrict__ EH, const bf8* __restrict__ EL,
        const float* __restrict__ enneg, float* __restrict__ bvv,
        float* __restrict__ b2a, int* __restrict__ iva) {
    __shared__ bf8 sEH[512];    // 8 vt * 64 lanes = 8KB
    __shared__ bf8 sEL[512];
    __shared__ float sen[128];

    int tid = threadIdx.x;
    int lane = tid & 63;
    int wv = tid >> 6;
    int ci = blockIdx.x >> 9;        // code split 0..3 (1024 codes)
    int pb = blockIdx.x & 511;       // point block (128 points)
    int base = pb * 128 + wv * 32;
    int col = lane & 15, kb = lane >> 4;

    bf8 xh[2], xl[2];
#pragma unroll
    for (int t = 0; t < 2; ++t) {
        int n = base + t * 16 + col;
        int b = n >> 12, pix = n & 4095;
        const float* fp = f + ((size_t)(b * C + kb * 8)) * 4096 + pix;
#pragma unroll
        for (int j = 0; j < 8; ++j) {
            float x = fp[(size_t)j * 4096];
            short hs;
            float hf = bf16rne_f(x, &hs);
            xh[t][j] = hs;
            xl[t][j] = bf16rne(x - hf);
        }
    }

    float best[8], best2[8];
#pragma unroll
    for (int e = 0; e < 8; ++e) { best[e] = -3.4e38f; best2[e] = -3.4e38f; }

    for (int ph = 0; ph < 8; ++ph) {
        if (ph) __syncthreads();
        int vt0 = ci * 64 + ph * 8;
        int off = vt0 * 64;
        sEH[tid]       = EH[off + tid];
        sEH[tid + 256] = EH[off + tid + 256];
        sEL[tid]       = EL[off + tid];
        sEL[tid + 256] = EL[off + tid + 256];
        if (tid < 128) sen[tid] = enneg[vt0 * 16 + tid];
        __syncthreads();
#pragma unroll
        for (int s2 = 0; s2 < 4; ++s2) {
            int s0 = 2 * s2, s1 = s0 + 1;
            bf8 eh0 = sEH[s0 * 64 + lane], el0 = sEL[s0 * 64 + lane];
            bf8 eh1 = sEH[s1 * 64 + lane], el1 = sEL[s1 * 64 + lane];
            float ng0 = sen[s0 * 16 + col], ng1 = sen[s1 * 16 + col];
            unsigned vtb0 = 63u - (unsigned)(ph * 8 + s0);
            unsigned vtb1 = 63u - (unsigned)(ph * 8 + s1);
#pragma unroll
            for (int t = 0; t < 2; ++t) {
                f4 a0 = {ng0, ng0, ng0, ng0};
                a0 = __builtin_amdgcn_mfma_f32_16x16x32_bf16(xh[t], eh0, a0, 0, 0, 0);
                a0 = __builtin_amdgcn_mfma_f32_16x16x32_bf16(xh[t], el0, a0, 0, 0, 0);
                a0 = __builtin_amdgcn_mfma_f32_16x16x32_bf16(xl[t], eh0, a0, 0, 0, 0);
                f4 a1 = {ng1, ng1, ng1, ng1};
                a1 = __builtin_amdgcn_mfma_f32_16x16x32_bf16(xh[t], eh1, a1, 0, 0, 0);
                a1 = __builtin_amdgcn_mfma_f32_16x16x32_bf16(xh[t], el1, a1, 0, 0, 0);
                a1 = __builtin_amdgcn_mfma_f32_16x16x32_bf16(xl[t], eh1, a1, 0, 0, 0);
#pragma unroll
                for (int r = 0; r < 4; ++r) {
                    int e = t * 4 + r;
                    float k0 = __uint_as_float((__float_as_uint(a0[r]) & 0xFFFFFFC0u) | vtb0);
                    float o0 = best[e];
                    best[e]  = fmaxf(o0, k0);
                    best2[e] = __builtin_amdgcn_fmed3f(o0, best2[e], k0);
                    float k1 = __uint_as_float((__float_as_uint(a1[r]) & 0xFFFFFFC0u) | vtb1);
                    float o1 = best[e];
                    best[e]  = fmaxf(o1, k1);
                    best2[e] = __builtin_amdgcn_fmed3f(o1, best2[e], k1);
                }
            }
        }
    }

    // decode + 16-col merge + per-split write
#pragma unroll
    for (int t = 0; t < 2; ++t) {
#pragma unroll
        for (int r = 0; r < 4; ++r) {
            float bb = best[t*4+r], b2 = best2[t*4+r];
            int vtl = 63 - (int)(__float_as_uint(bb) & 63u);
            int ii = (ci * 64 + vtl) * 16 + col;
#pragma unroll
            for (int m = 1; m < 16; m <<= 1) {
                float ob  = __shfl_xor(bb, m);
                float ob2 = __shfl_xor(b2, m);
                int   oi  = __shfl_xor(ii, m);
                b2 = fmaxf(fmaxf(b2, ob2), fminf(bb, ob));
                bool take = (ob > bb) || (ob == bb && oi < ii);
                ii = take ? oi : ii;
                bb = fmaxf(bb, ob);
            }
            if (col == 0) {
                int p = base + t * 16 + kb * 4 + r;
                int o = ci * NPTS + p;
                bvv[o] = bb; b2a[o] = b2; iva[o] = ii;
            }
        }
    }
}

// ---- merge 4 splits, write idx, flag ambiguous ----
__global__ void k_merge(const float* __restrict__ bvv, const float* __restrict__ b2a,
                        const int* __restrict__ iva, int* __restrict__ idx,
                        int* __restrict__ cnt, int* __restrict__ flags,
                        unsigned long long* __restrict__ fkey) {
    int n = blockIdx.x * 256 + threadIdx.x;
    float bb = bvv[n], b2 = b2a[n];
    int ii = iva[n];
#pragma unroll
    for (int s = 1; s < NSPLIT; ++s) {
        float ob  = bvv[s * NPTS + n];
        float ob2 = b2a[s * NPTS + n];
        int   oi  = iva[s * NPTS + n];
        b2 = fmaxf(fmaxf(b2, ob2), fminf(bb, ob));
        bool take = (ob > bb) || (ob == bb && oi < ii);
        ii = take ? oi : ii;
        bb = fmaxf(bb, ob);
    }
    idx[n] = ii;
    if (bb - b2 <= MARG) {
        int pos = atomicAdd(cnt, 1);
        flags[pos] = n;
        fkey[pos] = ~0ULL;
    }
}

// ---- exact fp32 recheck: 4 waves/point, 16 codes/lane, wave-reduce + 1 atomic ----
__global__ __launch_bounds__(256) void k_exact(const float* __restrict__ f,
        const float* __restrict__ emb, const float* __restrict__ enneg,
        const int* __restrict__ cnt, const int* __restrict__ flags,
        unsigned long long* __restrict__ fkey) {
    int nw = cnt[0] * 4;
    int wv = threadIdx.x >> 6, lane = threadIdx.x & 63;
    for (int w = blockIdx.x * 4 + wv; w < nw; w += gridDim.x * 4) {
        int fi = w >> 2, part = w & 3;
        int n = flags[fi];
        int b = n >> 12, pix = n & 4095;
        float x[C];
#pragma unroll
        for (int c = 0; c < C; ++c) x[c] = f[((size_t)b * C + c) * 4096 + pix];
        float bd = 3.4e38f;
        int bv = 0;
        int c0 = part * 1024 + lane * 16;
        for (int v2 = 0; v2 < 16; ++v2) {
            int code = c0 + v2;
            const float4* e4 = (const float4*)(emb + code * C);
            float d0 = -enneg[code], d1 = 0.f;   // 0.5||e||^2 - x.e
#pragma unroll
            for (int j = 0; j < 4; ++j) {
                float4 q = e4[j];
                d0 = fmaf(q.x, -x[4*j+0], d0);
                d0 = fmaf(q.y, -x[4*j+1], d0);
                d0 = fmaf(q.z, -x[4*j+2], d0);
                d0 = fmaf(q.w, -x[4*j+3], d0);
            }
#pragma unroll
            for (int j = 4; j < 8; ++j) {
                float4 q = e4[j];
                d1 = fmaf(q.x, -x[4*j+0], d1);
                d1 = fmaf(q.y, -x[4*j+1], d1);
                d1 = fmaf(q.z, -x[4*j+2], d1);
                d1 = fmaf(q.w, -x[4*j+3], d1);
            }
            float d = d0 + d1;
            if (d < bd) { bd = d; bv = code; }
        }
        unsigned long long k = ((unsigned long long)ford(bd) << 32) | (unsigned int)bv;
#pragma unroll
        for (int m = 1; m < 64; m <<= 1) {
            unsigned long long ok = __shfl_xor(k, m);
            k = ok < k ? ok : k;
        }
        if (lane == 0) atomicMin(&fkey[fi], k);
    }
}

__global__ void k_fix(const int* __restrict__ cnt, const int* __restrict__ flags,
                      const unsigned long long* __restrict__ fkey, int* __restrict__ idx) {
    int t = blockIdx.x * 256 + threadIdx.x;
    if (t < cnt[0]) idx[flags[t]] = (int)(fkey[t] & 0xFFFFu);
}

// ---- fused gather + conv3x3 + Phi + output + loss partials (8x8 tiles, 1024 blocks) ----
__global__ __launch_bounds__(256) void k_conv(const float* __restrict__ f,
                                              const float* __restrict__ emb,
                                              const int* __restrict__ idx,
                                              const float* __restrict__ wt,
                                              const float* __restrict__ cb,
                                              float* __restrict__ out,
                                              float* __restrict__ partial) {
    __shared__ float tile[100 * 36];   // [10][10][36] padded, 14.4KB
    __shared__ float red[256];

    int blk = blockIdx.x;
    int b = blk >> 6, t = blk & 63;
    int y0 = (t >> 3) * 8, x0 = (t & 7) * 8;
    int tid = threadIdx.x;

    if (tid < 100) {
        int gy = y0 + tid / 10 - 1;
        int gx = x0 + tid % 10 - 1;
        float4 e[8];
        if (gy >= 0 && gy < HH && gx >= 0 && gx < WW) {
            int id = idx[b * 4096 + gy * WW + gx];
            const float4* e4 = (const float4*)(emb + id * C);
#pragma unroll
            for (int j = 0; j < 8; ++j) e[j] = e4[j];
        } else {
#pragma unroll
            for (int j = 0; j < 8; ++j) e[j] = make_float4(0.f, 0.f, 0.f, 0.f);
        }
        float4* dst = (float4*)(tile + tid * 36);
#pragma unroll
        for (int j = 0; j < 8; ++j) dst[j] = e[j];
    }
    __syncthreads();

    int lane = tid & 63;
    int ow = __builtin_amdgcn_readfirstlane(tid >> 6);
    int px = lane & 7, py = lane >> 3;

    float acc[8];
    const float* cbp = cb + ow * 8;
#pragma unroll
    for (int j = 0; j < 8; ++j) acc[j] = cbp[j];

#pragma unroll
    for (int ky = 0; ky < 3; ++ky)
#pragma unroll
    for (int kx = 0; kx < 3; ++kx) {
        const float* trow = tile + ((py + ky) * 10 + px + kx) * 36;
#pragma unroll
        for (int i4 = 0; i4 < 8; ++i4) {
            float vv[4];
            *(float4*)vv = *(const float4*)(trow + i4 * 4);
#pragma unroll
            for (int j2 = 0; j2 < 4; ++j2) {
                int i = i4 * 4 + j2;
                const float* w8 = wt + ((i * 3 + ky) * 3 + kx) * C + ow * 8;
                float vj = vv[j2];
#pragma unroll
                for (int o = 0; o < 8; ++o) acc[o] = fmaf(vj, w8[o], acc[o]);
            }
        }
    }

    int y = y0 + py, x = x0 + px;
    const float* center = tile + ((py + 1) * 10 + (px + 1)) * 36 + ow * 8;
    float ls = 0.f;
#pragma unroll
    for (int o = 0; o < 8; ++o) {
        float fh = 0.5f * center[o] + 0.5f * acc[o];
        int oi = ((b * C + ow * 8 + o) * HH + y) * WW + x;
        out[oi] = fh;
        float e = fh - f[oi];
        ls = fmaf(e, e, ls);
    }

    red[tid] = ls;
    __syncthreads();
    for (int s = 128; s > 0; s >>= 1) {
        if (tid < s) red[tid] += red[tid + s];
        __syncthreads();
    }
    if (tid == 0) partial[blk] = red[0];
}

// ---- final loss reduce (1024 partials) ----
__global__ void k_final(const float* __restrict__ partial, float* __restrict__ out_loss) {
    __shared__ float red[256];
    int tid = threadIdx.x;
    red[tid] = partial[tid] + partial[tid + 256] + partial[tid + 512] + partial[tid + 768];
    __syncthreads();
    for (int s = 128; s > 0; s >>= 1) {
        if (tid < s) red[tid] += red[tid + s];
        __syncthreads();
    }
    if (tid == 0) out_loss[0] = 1.25f * red[0] / 2097152.0f;
}

extern "C" void kernel_launch(void* const* d_in, const int* in_sizes, int n_in,
                              void* d_out, int out_size, void* d_ws, size_t ws_size,
                              hipStream_t stream) {
    const float* f   = (const float*)d_in[0];
    const float* emb = (const float*)d_in[1];
    const float* cw  = (const float*)d_in[2];
    const float* cb  = (const float*)d_in[3];
    float* out = (float*)d_out;

    char* w = (char*)d_ws;
    float* enneg   = (float*)w;                 w += V * 4;
    float* wt      = (float*)w;                 w += C * C * 9 * 4;
    int*   idx     = (int*)w;                   w += NPTS * 4;
    int*   flags   = (int*)w;                   w += NPTS * 4;
    unsigned long long* fkey = (unsigned long long*)w; w += NPTS * 8;
    int*   cnt     = (int*)w;                   w += 256;
    float* partial = (float*)w;                 w += 1024 * 4;
    bf8*   EH      = (bf8*)w;                   w += 256 * 64 * 16;
    bf8*   EL      = (bf8*)w;                   w += 256 * 64 * 16;
    float* bvv     = (float*)w;                 w += NSPLIT * NPTS * 4;
    float* b2a     = (float*)w;                 w += NSPLIT * NPTS * 4;
    int*   iva     = (int*)w;                   w += NSPLIT * NPTS * 4;

    k_init0<<<1, 64, 0, stream>>>(cnt);
    k_en<<<V / 256, 256, 0, stream>>>(emb, enneg);
    k_wt<<<(C * C * 9 + 255) / 256, 256, 0, stream>>>(cw, wt);
    k_prep_e<<<64, 256, 0, stream>>>(emb, EH, EL);
    k_argmfma<<<512 * NSPLIT, 256, 0, stream>>>(f, EH, EL, enneg, bvv, b2a, iva);
    k_merge<<<NPTS / 256, 256, 0, stream>>>(bvv, b2a, iva, idx, cnt, flags, fkey);
    k_exact<<<1024, 256, 0, stream>>>(f, emb, enneg, cnt, flags, fkey);
    k_fix<<<NPTS / 256, 256, 0, stream>>>(cnt, flags, fkey, idx);
    k_conv<<<1024, 256, 0, stream>>>(f, emb, idx, wt, cb, out, partial);
    k_final<<<1, 256, 0, stream>>>(partial, out + 2097152);
}